// Round 8
// baseline (217.271 us; speedup 1.0000x reference)
//
#include <hip/hip_runtime.h>
#include <hip/hip_bf16.h>
#include <math.h>
#include <float.h>

// Problem constants (x: [8192,128] f32, n_images=2)
static constexpr int NN   = 8192;
static constexpr int DD   = 128;
static constexpr int PP   = 4096;
static constexpr int TT   = 64;                 // 128-row tiles per dim
static constexpr int NBLK = TT * (TT + 1) / 2;  // 2080 tile-pair blocks
static constexpr int NC   = NBLK * 2;           // 2 cands per block = 4160

struct Cand { float v; unsigned idx; };

using short8   = __attribute__((ext_vector_type(8))) short;
using f32x4    = __attribute__((ext_vector_type(4))) float;
using uint32x4 = __attribute__((ext_vector_type(4))) unsigned int;
using uint32x2 = __attribute__((ext_vector_type(2))) unsigned int;

__device__ __forceinline__ unsigned pk2(float lo, float hi) {
    unsigned a = (unsigned)__builtin_bit_cast(unsigned short, __float2bfloat16(lo));
    unsigned b = (unsigned)__builtin_bit_cast(unsigned short, __float2bfloat16(hi));
    return a | (b << 16);
}

__device__ __forceinline__ void push1(float& v1, unsigned& i1, float& v2, unsigned& i2,
                                      float w, unsigned j) {
    if (w > v1) { v2 = v1; i2 = i1; v1 = w; i1 = j; }
    else if (w > v2) { v2 = w; i2 = j; }
}

__device__ __forceinline__ void merge2(float& v1, unsigned& i1, float& v2, unsigned& i2,
                                       float w1, unsigned j1, float w2, unsigned j2) {
    if (w1 > v1) {
        float nv2; unsigned ni2;
        if (v1 >= w2) { nv2 = v1; ni2 = i1; } else { nv2 = w2; ni2 = j2; }
        v1 = w1; i1 = j1; v2 = nv2; i2 = ni2;
    } else if (w1 > v2) {
        v2 = w1; i2 = j1;
    }
}

// ---- kernel 0: pack x into MFMA-fragment-tiled bf16 layout + sim_self ----
// Group g = 16 rows; byte offset = g*4096 + c*256 + rloc*16 (c = 16B k-chunk).
// Wave fragment (group g, K-step s) = xq + g*4096 + s*1024 + lane*16.
// ALL producer stores are NON-TEMPORAL so lines land CLEAN in memory --
// consumer XCDs then fill their local L2 instead of hitting remote-dirty
// lines across the fabric (the suspected ~2 B/cyc/CU invariant of R4-R7).
__global__ __launch_bounds__(256) void k_prep(const float* __restrict__ x,
                                              char* __restrict__ xq,
                                              double* __restrict__ ss) {
    const int tid = threadIdx.x;
    if (blockIdx.x < 512) {
        int gg   = blockIdx.x * 256 + tid;   // 0..131071, one 16B output each
        int grp  = gg >> 8;                  // 0..511
        int c    = (gg >> 4) & 15;           // 0..15
        int rloc = gg & 15;                  // 0..15
        int r    = grp * 16 + rloc;          // 0..8191
        const float4* s = (const float4*)(x + (size_t)r * DD + c * 8);
        float4 f0 = s[0], f1 = s[1];
        uint32x4 o = {pk2(f0.x, f0.y), pk2(f0.z, f0.w), pk2(f1.x, f1.y), pk2(f1.z, f1.w)};
        __builtin_nontemporal_store(o, (uint32x4*)(xq + (size_t)gg * 16));
    } else {
        int b = blockIdx.x - 512;          // 0..63
        const int wv = tid >> 6, lane = tid & 63;
        #pragma unroll 4
        for (int u = 0; u < 16; ++u) {
            int p = b * 64 + wv * 16 + u;  // 0..4095
            const float* a  = x + (size_t)p * DD;
            const float* bb = a + DD;
            double s = (double)a[lane] * (double)bb[lane]
                     + (double)a[lane + 64] * (double)bb[lane + 64];
            #pragma unroll
            for (int off = 32; off >= 1; off >>= 1) s += __shfl_down(s, off);
            if (lane == 0) __builtin_nontemporal_store(s, &ss[p]);
        }
    }
}

// ---- kernel 1: LDS-free MFMA top-2. Block = 128x128 tile pair; wave = 64x64
// quadrant. ALL 32 fragments (A 16 + B 16) loaded upfront into named
// registers (max MLP); waves_per_eu pinned to 2 so the compiler has a
// 256-VGPR budget and no reason to shunt fragments into AGPRs / serialize
// loads through a small staging pool. ----
__global__ __launch_bounds__(256)
__attribute__((amdgpu_waves_per_eu(2, 2)))
void k_top2(const char* __restrict__ xq, Cand* __restrict__ cands) {
    __shared__ float sv1[4], sv2[4];
    __shared__ unsigned si1[4], si2[4];

    // decode linear block id -> (ti, tj), ti <= tj
    int rem = blockIdx.x;
    int ti = 0;
    while (rem >= TT - ti) { rem -= (TT - ti); ++ti; }
    int tj = ti + rem;

    const int tid  = threadIdx.x;
    const int wv   = tid >> 6;
    const int lane = tid & 63;
    const int quad = lane >> 4;
    const int r16  = lane & 15;
    const int wm   = wv >> 1;
    const int wn   = wv & 1;

    const char* fb = xq + (size_t)lane * 16;   // per-lane fragment base
    const int ig = ti * 8 + wm * 4;            // first A row-group
    const int jg = tj * 8 + wn * 4;            // first B row-group

    // ---- all 32 fragment loads issued before any use ----
    short8 af[4][4], bf[4][4];
    #pragma unroll
    for (int g = 0; g < 4; ++g)
        #pragma unroll
        for (int s = 0; s < 4; ++s) {
            af[g][s] = *(const short8*)(fb + (size_t)(ig + g) * 4096 + s * 1024);
            bf[g][s] = *(const short8*)(fb + (size_t)(jg + g) * 4096 + s * 1024);
        }

    float v1 = -INFINITY, v2 = -INFINITY;
    unsigned i1 = 0, i2 = 0;

    #pragma unroll
    for (int gm = 0; gm < 4; ++gm) {
        #pragma unroll
        for (int gn = 0; gn < 4; ++gn) {
            f32x4 a = __builtin_amdgcn_mfma_f32_16x16x32_bf16(
                af[gm][0], bf[gn][0], (f32x4){0.f, 0.f, 0.f, 0.f}, 0, 0, 0);
            #pragma unroll
            for (int s = 1; s < 4; ++s)
                a = __builtin_amdgcn_mfma_f32_16x16x32_bf16(
                    af[gm][s], bf[gn][s], a, 0, 0, 0);
            // C/D layout: col = lane&15, row = quad*4 + reg
            int gj  = (jg + gn) * 16 + r16;
            int gib = (ig + gm) * 16 + quad * 4;
            #pragma unroll
            for (int reg = 0; reg < 4; ++reg) {
                int gi = gib + reg;
                if (gi < gj)
                    push1(v1, i1, v2, i2, a[reg], (unsigned)(gi * NN + gj));
            }
        }
    }

    // wave top-2 reduction, then block reduce via tiny LDS
    #pragma unroll
    for (int off = 32; off >= 1; off >>= 1) {
        float    w1 = __shfl_down(v1, off);
        unsigned j1 = (unsigned)__shfl_down((int)i1, off);
        float    w2 = __shfl_down(v2, off);
        unsigned j2 = (unsigned)__shfl_down((int)i2, off);
        merge2(v1, i1, v2, i2, w1, j1, w2, j2);
    }
    if (lane == 0) { sv1[wv] = v1; si1[wv] = i1; sv2[wv] = v2; si2[wv] = i2; }
    __syncthreads();
    if (tid == 0) {
        for (int w = 1; w < 4; ++w)
            merge2(v1, i1, v2, i2, sv1[w], si1[w], sv2[w], si2[w]);
        uint32x2 c0 = {__builtin_bit_cast(unsigned, v1), i1};
        uint32x2 c1 = {__builtin_bit_cast(unsigned, v2), i2};
        __builtin_nontemporal_store(c0, (uint32x2*)&cands[blockIdx.x * 2]);
        __builtin_nontemporal_store(c1, (uint32x2*)&cands[blockIdx.x * 2 + 1]);
    }
}

// ---- kernel 2: approx top-2 -> exact recheck (double) -> final mean ----
__global__ __launch_bounds__(256) void k_final(const float* __restrict__ x,
                                               const double* __restrict__ ss,
                                               const Cand* __restrict__ cands,
                                               float* __restrict__ out) {
    __shared__ float redv[8];
    __shared__ float s_thresh;
    __shared__ int cnt;
    __shared__ unsigned qidx[128];
    __shared__ double qex[128];
    __shared__ double sd1, sd2;
    __shared__ unsigned stopi;
    __shared__ double sacc[256];

    const int tid  = threadIdx.x;
    const int wv   = tid >> 6;
    const int lane = tid & 63;
    if (tid == 0) cnt = 0;

    // Phase A: approx global top-2 VALUES
    float v1 = -INFINITY, v2 = -INFINITY;
    for (int e = tid; e < NC; e += 256) {
        float v = cands[e].v;
        if (v > v1) { v2 = v1; v1 = v; }
        else if (v > v2) v2 = v;
    }
    #pragma unroll
    for (int off = 32; off >= 1; off >>= 1) {
        float w1 = __shfl_down(v1, off);
        float w2 = __shfl_down(v2, off);
        if (w1 > v1) { v2 = (v1 >= w2) ? v1 : w2; v1 = w1; }
        else if (w1 > v2) v2 = w1;
    }
    if (lane == 0) { redv[wv * 2] = v1; redv[wv * 2 + 1] = v2; }
    __syncthreads();
    if (tid == 0) {
        float a1 = -INFINITY, a2 = -INFINITY;
        for (int e = 0; e < 8; ++e) {
            float v = redv[e];
            if (v > a1) { a2 = a1; a1 = v; }
            else if (v > a2) a2 = v;
        }
        s_thresh = a2 - 1.0f;   // margin >> bf16 dot-product error bound (~0.1)
    }
    __syncthreads();
    const float thresh = s_thresh;

    // Phase B: gather all candidates within margin of approx top-2
    for (int e = tid; e < NC; e += 256) {
        if (cands[e].v >= thresh) {
            int k = atomicAdd(&cnt, 1);
            if (k < 128) qidx[k] = cands[e].idx;
        }
    }
    __syncthreads();
    const int n = cnt < 128 ? cnt : 128;

    // Phase C: exact double dot per qualifying candidate (one wave each)
    for (int c = wv; c < n; c += 4) {
        unsigned idx = qidx[c];
        unsigned gi = idx >> 13;
        unsigned gj = idx & 8191;
        const float* pa = x + (size_t)gi * DD;
        const float* pb = x + (size_t)gj * DD;
        double s = (double)pa[lane] * (double)pb[lane]
                 + (double)pa[lane + 64] * (double)pb[lane + 64];
        #pragma unroll
        for (int off = 32; off >= 1; off >>= 1) s += __shfl_down(s, off);
        if (lane == 0) qex[c] = s;
    }
    __syncthreads();

    // Phase D: exact top-2 over rechecked candidates
    if (tid == 0) {
        double d1 = -DBL_MAX, d2 = -DBL_MAX;
        unsigned bi = 0;
        for (int c = 0; c < n; ++c) {
            double v = qex[c];
            if (v > d1) { d2 = d1; d1 = v; bi = qidx[c]; }
            else if (v > d2) d2 = v;
        }
        sd1 = d1; sd2 = d2; stopi = bi;
    }
    __syncthreads();

    const double top1 = sd1, top2 = sd2;
    const unsigned topi = stopi;

    // Phase E: mean(sim_oth / sim_self)
    double acc = 0.0;
    for (int p = tid; p < PP; p += 256) {
        unsigned selfidx = (unsigned)(p * NN + p + 1);
        double so = (topi == selfidx) ? top2 : top1;
        acc += so / ss[p];
    }
    sacc[tid] = acc;
    __syncthreads();
    for (int s = 128; s >= 1; s >>= 1) {
        if (tid < s) sacc[tid] += sacc[tid + s];
        __syncthreads();
    }
    if (tid == 0) out[0] = (float)(sacc[0] / (double)PP);
}

extern "C" void kernel_launch(void* const* d_in, const int* in_sizes, int n_in,
                              void* d_out, int out_size, void* d_ws, size_t ws_size,
                              hipStream_t stream) {
    (void)in_sizes; (void)n_in; (void)out_size; (void)ws_size;
    const float* x = (const float*)d_in[0];
    float* out = (float*)d_out;

    double* ss  = (double*)d_ws;                 // 32 KB
    Cand* cands = (Cand*)((char*)d_ws + 32768);  // ~33 KB
    char* xq    = (char*)d_ws + 131072;          // 2 MB fragment-tiled bf16

    k_prep<<<576, 256, 0, stream>>>(x, xq, ss);
    k_top2<<<NBLK, 256, 0, stream>>>(xq, cands);
    k_final<<<1, 256, 0, stream>>>(x, ss, cands, out);
}

// Round 9
// 187.761 us; speedup vs baseline: 1.1572x; 1.1572x over previous
//
#include <hip/hip_runtime.h>
#include <hip/hip_bf16.h>
#include <math.h>
#include <float.h>

// Problem constants (x: [8192,128] f32, n_images=2)
static constexpr int NN   = 8192;
static constexpr int DD   = 128;
static constexpr int PP   = 4096;
static constexpr int TT   = 32;                 // 256-row tiles per dim
static constexpr int NBLK = TT * (TT + 1) / 2;  // 528 tile-pair blocks
static constexpr int NC   = NBLK * 2;           // 2 cands per block = 1056

struct Cand { float v; unsigned idx; };

using short8 = __attribute__((ext_vector_type(8))) short;
using f32x4  = __attribute__((ext_vector_type(4))) float;

__device__ __forceinline__ unsigned pk2(float lo, float hi) {
    unsigned a = (unsigned)__builtin_bit_cast(unsigned short, __float2bfloat16(lo));
    unsigned b = (unsigned)__builtin_bit_cast(unsigned short, __float2bfloat16(hi));
    return a | (b << 16);
}

__device__ __forceinline__ void push1(float& v1, unsigned& i1, float& v2, unsigned& i2,
                                      float w, unsigned j) {
    if (w > v1) { v2 = v1; i2 = i1; v1 = w; i1 = j; }
    else if (w > v2) { v2 = w; i2 = j; }
}

__device__ __forceinline__ void merge2(float& v1, unsigned& i1, float& v2, unsigned& i2,
                                       float w1, unsigned j1, float w2, unsigned j2) {
    if (w1 > v1) {
        float nv2; unsigned ni2;
        if (v1 >= w2) { nv2 = v1; ni2 = i1; } else { nv2 = w2; ni2 = j2; }
        v1 = w1; i1 = j1; v2 = nv2; i2 = ni2;
    } else if (w1 > v2) {
        v2 = w1; i2 = j1;
    }
}

// ---- kernel 0: pack x into MFMA-fragment-tiled bf16 layout + sim_self ----
// Group g = 16 rows; byte offset = g*4096 + c*256 + rloc*16 (c = 16B k-chunk).
// Wave fragment (group g, K-step s) = xq + g*4096 + s*1024 + lane*16.
__global__ __launch_bounds__(256) void k_prep(const float* __restrict__ x,
                                              char* __restrict__ xq,
                                              double* __restrict__ ss) {
    const int tid = threadIdx.x;
    if (blockIdx.x < 512) {
        int gg   = blockIdx.x * 256 + tid;   // 0..131071, one 16B output each
        int grp  = gg >> 8;                  // 0..511
        int c    = (gg >> 4) & 15;           // 0..15
        int rloc = gg & 15;                  // 0..15
        int r    = grp * 16 + rloc;          // 0..8191
        const float4* s = (const float4*)(x + (size_t)r * DD + c * 8);
        float4 f0 = s[0], f1 = s[1];
        uint4 o = {pk2(f0.x, f0.y), pk2(f0.z, f0.w), pk2(f1.x, f1.y), pk2(f1.z, f1.w)};
        *(uint4*)(xq + (size_t)gg * 16) = o;
    } else {
        int b = blockIdx.x - 512;          // 0..63
        const int wv = tid >> 6, lane = tid & 63;
        #pragma unroll 4
        for (int u = 0; u < 16; ++u) {
            int p = b * 64 + wv * 16 + u;  // 0..4095
            const float* a  = x + (size_t)p * DD;
            const float* bb = a + DD;
            double s = (double)a[lane] * (double)bb[lane]
                     + (double)a[lane + 64] * (double)bb[lane + 64];
            #pragma unroll
            for (int off = 32; off >= 1; off >>= 1) s += __shfl_down(s, off);
            if (lane == 0) ss[p] = s;
        }
    }
}

// ---- kernel 1: 256x256 tile-pair MFMA top-2. 1024 threads = 4x4 waves of
// 64x64 quadrants. A+B tiles (K=128 fully resident) staged once into 128 KB
// LDS via coalesced global loads + conflict-free ds_write_b128 (lane*16).
// Global traffic: 528 x 128 KB = 67.6 MB (4x less than the 128-tile scheme,
// attacking the empirically-capped ~2.5 TB/s chip-wide read path). ----
__global__ __launch_bounds__(1024) void k_top2(const char* __restrict__ xq,
                                               Cand* __restrict__ cands) {
    __shared__ __align__(16) char AsB[65536];   // 16 groups x 4096 B
    __shared__ __align__(16) char BsB[65536];
    __shared__ float sv1[16], sv2[16];
    __shared__ unsigned si1[16], si2[16];

    // decode linear block id -> (ti, tj), ti <= tj
    int rem = blockIdx.x;
    int ti = 0;
    while (rem >= TT - ti) { rem -= (TT - ti); ++ti; }
    int tj = ti + rem;

    const int tid  = threadIdx.x;
    const int wv   = tid >> 6;      // 0..15
    const int lane = tid & 63;
    const int quad = lane >> 4;
    const int r16  = lane & 15;
    const int wm   = wv >> 2;       // wave row 0..3
    const int wn   = wv & 3;        // wave col 0..3

    // ---- stage: wave w copies chunks w*8 .. w*8+7 (A: 0..63, B: 64..127).
    // Each chunk = 1 KB = (group g, K-step s); LDS offset preserves the
    // fragment layout so readback is lane*16 (bank-balanced). ----
    #pragma unroll
    for (int t = 0; t < 8; ++t) {
        int ch  = wv * 8 + t;          // 0..127
        int isB = ch >> 6;
        int c   = ch & 63;             // g*4 + s
        const char* src = xq + ((size_t)((isB ? tj : ti) * 16) * 4096)
                        + (size_t)c * 1024 + (size_t)lane * 16;
        short8 d = *(const short8*)src;
        char* dst = (isB ? BsB : AsB) + c * 1024 + lane * 16;
        *(short8*)dst = d;
    }
    __syncthreads();

    // B fragments resident: wave's 4 col-groups (wn*4 .. wn*4+3)
    short8 bf[4][4];
    #pragma unroll
    for (int gn = 0; gn < 4; ++gn)
        #pragma unroll
        for (int s = 0; s < 4; ++s)
            bf[gn][s] = *(const short8*)(BsB + (wn * 4 + gn) * 4096
                                         + s * 1024 + lane * 16);

    float v1 = -INFINITY, v2 = -INFINITY;
    unsigned i1 = 0, i2 = 0;

    #pragma unroll
    for (int gm = 0; gm < 4; ++gm) {
        short8 af[4];
        #pragma unroll
        for (int s = 0; s < 4; ++s)
            af[s] = *(const short8*)(AsB + (wm * 4 + gm) * 4096
                                     + s * 1024 + lane * 16);
        #pragma unroll
        for (int gn = 0; gn < 4; ++gn) {
            f32x4 a = __builtin_amdgcn_mfma_f32_16x16x32_bf16(
                af[0], bf[gn][0], (f32x4){0.f, 0.f, 0.f, 0.f}, 0, 0, 0);
            #pragma unroll
            for (int s = 1; s < 4; ++s)
                a = __builtin_amdgcn_mfma_f32_16x16x32_bf16(
                    af[s], bf[gn][s], a, 0, 0, 0);
            // C/D layout: col = lane&15 (B row), row = quad*4 + reg (A row)
            int gj  = tj * 256 + (wn * 4 + gn) * 16 + r16;
            int gib = ti * 256 + (wm * 4 + gm) * 16 + quad * 4;
            #pragma unroll
            for (int reg = 0; reg < 4; ++reg) {
                int gi = gib + reg;
                if (gi < gj)
                    push1(v1, i1, v2, i2, a[reg], (unsigned)(gi * NN + gj));
            }
        }
    }

    // wave top-2 reduction, then block reduce over 16 waves
    #pragma unroll
    for (int off = 32; off >= 1; off >>= 1) {
        float    w1 = __shfl_down(v1, off);
        unsigned j1 = (unsigned)__shfl_down((int)i1, off);
        float    w2 = __shfl_down(v2, off);
        unsigned j2 = (unsigned)__shfl_down((int)i2, off);
        merge2(v1, i1, v2, i2, w1, j1, w2, j2);
    }
    if (lane == 0) { sv1[wv] = v1; si1[wv] = i1; sv2[wv] = v2; si2[wv] = i2; }
    __syncthreads();
    if (tid == 0) {
        for (int w = 1; w < 16; ++w)
            merge2(v1, i1, v2, i2, sv1[w], si1[w], sv2[w], si2[w]);
        cands[blockIdx.x * 2]     = {v1, i1};
        cands[blockIdx.x * 2 + 1] = {v2, i2};
    }
}

// ---- kernel 2: approx top-2 -> exact recheck (double) -> final mean ----
__global__ __launch_bounds__(256) void k_final(const float* __restrict__ x,
                                               const double* __restrict__ ss,
                                               const Cand* __restrict__ cands,
                                               float* __restrict__ out) {
    __shared__ float redv[8];
    __shared__ float s_thresh;
    __shared__ int cnt;
    __shared__ unsigned qidx[128];
    __shared__ double qex[128];
    __shared__ double sd1, sd2;
    __shared__ unsigned stopi;
    __shared__ double sacc[256];

    const int tid  = threadIdx.x;
    const int wv   = tid >> 6;
    const int lane = tid & 63;
    if (tid == 0) cnt = 0;

    // Phase A: approx global top-2 VALUES
    float v1 = -INFINITY, v2 = -INFINITY;
    for (int e = tid; e < NC; e += 256) {
        float v = cands[e].v;
        if (v > v1) { v2 = v1; v1 = v; }
        else if (v > v2) v2 = v;
    }
    #pragma unroll
    for (int off = 32; off >= 1; off >>= 1) {
        float w1 = __shfl_down(v1, off);
        float w2 = __shfl_down(v2, off);
        if (w1 > v1) { v2 = (v1 >= w2) ? v1 : w2; v1 = w1; }
        else if (w1 > v2) v2 = w1;
    }
    if (lane == 0) { redv[wv * 2] = v1; redv[wv * 2 + 1] = v2; }
    __syncthreads();
    if (tid == 0) {
        float a1 = -INFINITY, a2 = -INFINITY;
        for (int e = 0; e < 8; ++e) {
            float v = redv[e];
            if (v > a1) { a2 = a1; a1 = v; }
            else if (v > a2) a2 = v;
        }
        s_thresh = a2 - 1.0f;   // margin >> bf16 dot-product error bound (~0.1)
    }
    __syncthreads();
    const float thresh = s_thresh;

    // Phase B: gather all candidates within margin of approx top-2
    for (int e = tid; e < NC; e += 256) {
        if (cands[e].v >= thresh) {
            int k = atomicAdd(&cnt, 1);
            if (k < 128) qidx[k] = cands[e].idx;
        }
    }
    __syncthreads();
    const int n = cnt < 128 ? cnt : 128;

    // Phase C: exact double dot per qualifying candidate (one wave each)
    for (int c = wv; c < n; c += 4) {
        unsigned idx = qidx[c];
        unsigned gi = idx >> 13;
        unsigned gj = idx & 8191;
        const float* pa = x + (size_t)gi * DD;
        const float* pb = x + (size_t)gj * DD;
        double s = (double)pa[lane] * (double)pb[lane]
                 + (double)pa[lane + 64] * (double)pb[lane + 64];
        #pragma unroll
        for (int off = 32; off >= 1; off >>= 1) s += __shfl_down(s, off);
        if (lane == 0) qex[c] = s;
    }
    __syncthreads();

    // Phase D: exact top-2 over rechecked candidates
    if (tid == 0) {
        double d1 = -DBL_MAX, d2 = -DBL_MAX;
        unsigned bi = 0;
        for (int c = 0; c < n; ++c) {
            double v = qex[c];
            if (v > d1) { d2 = d1; d1 = v; bi = qidx[c]; }
            else if (v > d2) d2 = v;
        }
        sd1 = d1; sd2 = d2; stopi = bi;
    }
    __syncthreads();

    const double top1 = sd1, top2 = sd2;
    const unsigned topi = stopi;

    // Phase E: mean(sim_oth / sim_self)
    double acc = 0.0;
    for (int p = tid; p < PP; p += 256) {
        unsigned selfidx = (unsigned)(p * NN + p + 1);
        double so = (topi == selfidx) ? top2 : top1;
        acc += so / ss[p];
    }
    sacc[tid] = acc;
    __syncthreads();
    for (int s = 128; s >= 1; s >>= 1) {
        if (tid < s) sacc[tid] += sacc[tid + s];
        __syncthreads();
    }
    if (tid == 0) out[0] = (float)(sacc[0] / (double)PP);
}

extern "C" void kernel_launch(void* const* d_in, const int* in_sizes, int n_in,
                              void* d_out, int out_size, void* d_ws, size_t ws_size,
                              hipStream_t stream) {
    (void)in_sizes; (void)n_in; (void)out_size; (void)ws_size;
    const float* x = (const float*)d_in[0];
    float* out = (float*)d_out;

    double* ss  = (double*)d_ws;                 // 32 KB
    Cand* cands = (Cand*)((char*)d_ws + 32768);  // ~8.5 KB
    char* xq    = (char*)d_ws + 131072;          // 2 MB fragment-tiled bf16

    k_prep<<<576, 256, 0, stream>>>(x, xq, ss);
    k_top2<<<NBLK, 1024, 0, stream>>>(xq, cands);
    k_final<<<1, 256, 0, stream>>>(x, ss, cands, out);
}